// Round 17
// baseline (123.927 us; speedup 1.0000x reference)
//
#include <hip/hip_runtime.h>
#include <hip/hip_bf16.h>
#include <stdint.h>

typedef float  f32x4 __attribute__((ext_vector_type(4)));
typedef short  s16x8 __attribute__((ext_vector_type(8)));

#define NB    8
#define CIN   64
#define COUT  64
#define HH    128
#define WW    512
#define NTAP  17
#define PADW  152
#define WSPAN 256                 // w per block
#define BROWS (WSPAN + 2 * PADW)  // 560 LDS rows
#define HW    (HH * WW)

// ---------------------------------------------------------------------------
// weights in A-fragment order: byte off = (2t+p)*4096 + m*1024 + lane*16
__global__ __launch_bounds__(256) void prep_wfrag(
        const float* __restrict__ W, const float* __restrict__ Bv,
        __hip_bfloat16* __restrict__ wf, float* __restrict__ bsum) {
    int idx = blockIdx.x * 256 + threadIdx.x;      // 69,632 total
    if (idx < NTAP * 2 * 4 * 64 * 8) {
        int j  = idx & 7;
        int l  = (idx >> 3) & 63;
        int m  = (idx >> 9) & 3;
        int pp = (idx >> 11) & 1;
        int t  = idx >> 12;
        int ci = pp * 32 + 8 * (l >> 4) + j;
        int co = 16 * m + (l & 15);
        float v;
        if (t == 0) {
            v = 0.f;
            #pragma unroll
            for (int i = 0; i < NB; ++i) v += W[((i * COUT + co) * CIN + ci) * 3 + 1];
        } else if (t <= 8) {
            v = W[(((t - 1) * COUT + co) * CIN + ci) * 3 + 0];
        } else {
            v = W[(((t - 9) * COUT + co) * CIN + ci) * 3 + 2];
        }
        wf[idx] = __float2bfloat16(v);
    }
    if (idx < COUT) {
        float s = 0.f;
        #pragma unroll
        for (int i = 0; i < NB; ++i) s += Bv[i * COUT + idx];
        bsum[idx] = s;
    }
}

static constexpr int OFFS[NTAP] = {0, -48, -76, -96, -111, -124, -135, -144, -152,
                                      48,  76,  96,  111,  124,  135,  144,  152};

#define SB __builtin_amdgcn_sched_barrier(0)

#define LOADAF(AF, T0, CNT)                                                    \
    _Pragma("unroll")                                                          \
    for (int i = 0; i < (CNT); ++i)                                            \
        _Pragma("unroll")                                                      \
        for (int mm = 0; mm < 2; ++mm)                                         \
            AF[i][mm] = *reinterpret_cast<const s16x8*>(                       \
                wbase + ((T0) + i) * 8192 + (2 * mg + mm) * 1024);

#define COMPTAPS(AF, T0, CNT)                                                  \
    _Pragma("unroll")                                                          \
    for (int i = 0; i < (CNT); ++i) {                                          \
        const int t      = (T0) + i;                                           \
        const int ldsrow = rowb + OFFS[t];                                     \
        const int slot   = lhi ^ ((ldsrow >> 1) & 3);                          \
        const char* bbase = smem + ldsrow * 64 + slot * 16;                    \
        s16x8 bfr[8];                                                          \
        _Pragma("unroll")                                                      \
        for (int n = 0; n < 8; ++n)                                            \
            bfr[n] = *reinterpret_cast<const s16x8*>(bbase + n * 1024);        \
        _Pragma("unroll")                                                      \
        for (int mm = 0; mm < 2; ++mm)                                         \
            _Pragma("unroll")                                                  \
            for (int n = 0; n < 8; ++n)                                        \
                acc[mm][n] = __builtin_amdgcn_mfma_f32_16x16x32_bf16(          \
                    AF[i][mm], bfr[n], acc[mm][n], 0, 0, 0);                   \
    }

// compute one p-half: 6 af ping-pong batches (tap order rotated per mg group)
#define PHASE_SCHED(B1,C1, B2,C2, B3,C3, B4,C4, B5,C5, B6,C6)                  \
    {                                                                          \
        s16x8 afA[3][2], afB[3][2];                                            \
        LOADAF(afA, B1, C1)   SB;                                              \
        LOADAF(afB, B2, C2)   SB;                                              \
        COMPTAPS(afA, B1, C1) SB;                                              \
        LOADAF(afA, B3, C3)   SB;                                              \
        COMPTAPS(afB, B2, C2) SB;                                              \
        LOADAF(afB, B4, C4)   SB;                                              \
        COMPTAPS(afA, B3, C3) SB;                                              \
        LOADAF(afA, B5, C5)   SB;                                              \
        COMPTAPS(afB, B4, C4) SB;                                              \
        LOADAF(afB, B6, C6)   SB;                                              \
        COMPTAPS(afA, B5, C5) SB;                                              \
        COMPTAPS(afB, B6, C6) SB;                                              \
    }

// Non-persistent multi-block main: 2048 blocks x 256 thr (4 waves). Block =
// one (row, w-half): {stage p0; sync; compute; sync; stage p1; sync; compute;
// store}. Single 35,840B LDS buffer -> 3-4 blocks/CU = 12-16 waves/CU in
// INDEPENDENT barrier domains: other blocks' compute covers this block's
// stage/drain stalls (m114 — R5's 2-block/CU beat every 1-block persistent
// schedule R8-R16). Halo zeros free: OOB staging lanes write 0 (gw 4-aligned,
// 152%4==0, so a float4 never straddles the image edge). MFMA loop, slot
// XOR swizzle, af ping-pong, mg tap-rotation identical to verified R15.
__global__ __launch_bounds__(256, 3) void hdc_mfma(
        const float* __restrict__ x, const __hip_bfloat16* __restrict__ wf,
        const float* __restrict__ bsum, float* __restrict__ out) {
    __shared__ __align__(16) char smem[BROWS * 64];    // 35,840 B

    const int tid  = threadIdx.x;
    const int wv   = tid >> 6;                     // wave 0..3
    const int lane = tid & 63;
    const int l15  = lane & 15;
    const int lhi  = lane >> 4;
    const int mg   = wv >> 1;                      // m-pair 0/1 (co 32-half)
    const int ws   = wv & 1;                       // w-slice 0/1
    const int c    = tid >> 6;                     // staging chunk 0..3 (= wv)
    const int wl   = tid & 63;                     // staging w/4 index
    const int bid  = blockIdx.x;
    const int row  = bid >> 1;                     // (b,h) row 0..1023
    const int wh   = bid & 1;                      // w-half
    const int b    = row >> 7, h = row & 127;
    const int wlo  = ws * 128;
    const int rowb = PADW + wlo + l15;

    f32x4 acc[2][8];
    #pragma unroll
    for (int mm = 0; mm < 2; ++mm) {
        f32x4 bi = *reinterpret_cast<const f32x4*>(
            bsum + mg * 32 + 16 * mm + 4 * lhi);
        #pragma unroll
        for (int n = 0; n < 8; ++n) acc[mm][n] = bi;
    }

    // stage p-half: 3 rounds x (8 cond float4 loads -> cvt -> 4 swizzled b128)
    auto STAGE = [&](int p) {
        #pragma unroll
        for (int q = 0; q < 3; ++q) {
            const int r0 = q * 256 + wl * 4;
            if (r0 < BROWS) {
                const int gw = wh * WSPAN + r0 - PADW;     // 4-aligned
                const bool in = (gw >= 0) && (gw < WW);
                const float* src = x +
                    (((size_t)(b * CIN + p * 32 + c * 8) * HH + h) * WW);
                float4 xv[8];
                #pragma unroll
                for (int j = 0; j < 8; ++j) {
                    float4 v{0.f, 0.f, 0.f, 0.f};
                    if (in) v = *reinterpret_cast<const float4*>(
                                    src + (size_t)j * HW + gw);
                    xv[j] = v;
                }
                #pragma unroll
                for (int k = 0; k < 4; ++k) {
                    const int r    = r0 + k;
                    const int slot = c ^ ((r >> 1) & 3);
                    union { __hip_bfloat16 hs[8]; int4 iv; } pk;
                    #pragma unroll
                    for (int j = 0; j < 8; ++j)
                        pk.hs[j] = __float2bfloat16(((const float*)&xv[j])[k]);
                    *reinterpret_cast<int4*>(smem + r * 64 + slot * 16) = pk.iv;
                }
            }
        }
    };

    #pragma unroll
    for (int p = 0; p < 2; ++p) {
        if (p) __syncthreads();                    // all waves done reading p0
        STAGE(p);
        __syncthreads();                           // staging visible to all

        const char* wbase = (const char*)wf + p * 4096 + lane * 16;
        if (mg == 0) {
            PHASE_SCHED(0,3, 3,3, 6,3, 9,3, 12,3, 15,2)
        } else {
            PHASE_SCHED(9,3, 12,3, 15,2, 0,3, 3,3, 6,3)
        }
    }

    // epilogue: ReLU + store. D layout: col=l15 (w), row=4*lhi+rr (co)
    float* obase = out +
        (((size_t)b * COUT + mg * 32 + 4 * lhi) * HH + h) * WW +
        wh * WSPAN + wlo + l15;
    #pragma unroll
    for (int mm = 0; mm < 2; ++mm)
        #pragma unroll
        for (int n = 0; n < 8; ++n)
            #pragma unroll
            for (int rr = 0; rr < 4; ++rr) {
                float v = acc[mm][n][rr];
                obase[(size_t)(16 * mm + rr) * HW + 16 * n] = v > 0.f ? v : 0.f;
            }
}

// ---------------------------------------------------------------------------
// FALLBACK (round-1 fp32 kernel) if ws_size is too small for weight scratch
// ---------------------------------------------------------------------------
#define CI_STAGE 16
#define XROW 816

__global__ void prep_weff_fb(const float* __restrict__ W, const float* __restrict__ Bv,
                             float* __restrict__ weff, float* __restrict__ bsum) {
    int idx = blockIdx.x * 256 + threadIdx.x;
    if (idx < CIN * NTAP * COUT) {
        int co = idx & 63;
        int t  = (idx >> 6) % NTAP;
        int ci = idx / (NTAP * COUT);
        float v;
        if (t == 0) {
            v = 0.f;
            #pragma unroll
            for (int i = 0; i < NB; ++i) v += W[(((i * COUT + co) * CIN + ci) * 3) + 1];
        } else if (t <= 8) {
            v = W[((((t - 1) * COUT + co) * CIN + ci) * 3) + 0];
        } else {
            v = W[((((t - 9) * COUT + co) * CIN + ci) * 3) + 2];
        }
        weff[(ci * NTAP + t) * COUT + co] = v;
    }
    if (idx < COUT) {
        float s = 0.f;
        #pragma unroll
        for (int i = 0; i < NB; ++i) s += Bv[i * COUT + idx];
        bsum[idx] = s;
    }
}

__global__ __launch_bounds__(256, 2) void hdc_fb(
        const float* __restrict__ x, const float* __restrict__ weff,
        const float* __restrict__ bsum, float* __restrict__ out) {
    __shared__ float xsf[CI_STAGE][XROW];
    const int bh  = blockIdx.x;
    const int b   = bh >> 7;
    const int h   = bh & (HH - 1);
    const int tid = threadIdx.x;
    const int cg  = tid >> 5;
    const int wl  = tid & 31;
    float acc[8][16];
    #pragma unroll
    for (int j = 0; j < 8; ++j) {
        const float bj = bsum[cg * 8 + j];
        #pragma unroll
        for (int i = 0; i < 16; ++i) acc[j][i] = bj;
    }
    const float* xrowbase = x + ((size_t)(b * CIN) * HH + h) * WW;
    for (int s = 0; s < CIN / CI_STAGE; ++s) {
        __syncthreads();
        for (int f = tid; f < CI_STAGE * PADW; f += 256) {
            int r = f / PADW, cc = f - r * PADW;
            xsf[r][cc] = 0.f;
            xsf[r][PADW + WW + cc] = 0.f;
        }
        #pragma unroll
        for (int j = 0; j < 8; ++j) {
            int flat = j * 256 + tid;
            int r = flat >> 7, c4 = flat & 127;
            const float4 v = *reinterpret_cast<const float4*>(
                xrowbase + (size_t)(s * CI_STAGE + r) * HW + c4 * 4);
            *reinterpret_cast<float4*>(&xsf[r][PADW + c4 * 4]) = v;
        }
        __syncthreads();
        for (int r = 0; r < CI_STAGE; ++r) {
            const int ci = s * CI_STAGE + r;
            const float* wrow = weff + (size_t)(ci * NTAP) * COUT + cg * 8;
            const float* xr   = &xsf[r][PADW + wl];
            #pragma unroll
            for (int t = 0; t < NTAP; ++t) {
                const float4 w0 = *reinterpret_cast<const float4*>(wrow + t * COUT);
                const float4 w1 = *reinterpret_cast<const float4*>(wrow + t * COUT + 4);
                float xvv[16];
                #pragma unroll
                for (int i = 0; i < 16; ++i) xvv[i] = xr[OFFS[t] + 32 * i];
                const float wv2[8] = {w0.x, w0.y, w0.z, w0.w, w1.x, w1.y, w1.z, w1.w};
                #pragma unroll
                for (int j = 0; j < 8; ++j)
                    #pragma unroll
                    for (int i = 0; i < 16; ++i)
                        acc[j][i] = fmaf(wv2[j], xvv[i], acc[j][i]);
            }
        }
    }
    float* outbase = out + (((size_t)b * COUT + cg * 8) * HH + h) * WW + wl;
    #pragma unroll
    for (int j = 0; j < 8; ++j)
        #pragma unroll
        for (int i = 0; i < 16; ++i) {
            float v = acc[j][i];
            outbase[(size_t)j * HW + 32 * i] = v > 0.f ? v : 0.f;
        }
}

// ---------------------------------------------------------------------------

extern "C" void kernel_launch(void* const* d_in, const int* in_sizes, int n_in,
                              void* d_out, int out_size, void* d_ws, size_t ws_size,
                              hipStream_t stream) {
    const float* x  = (const float*)d_in[0];
    const float* W  = (const float*)d_in[1];
    const float* Bv = (const float*)d_in[2];
    float* out = (float*)d_out;

    const size_t need = 139264 + 256;              // wf + bsum

    if (ws_size >= need) {
        __hip_bfloat16* wf = (__hip_bfloat16*)d_ws;               // 139,264 B
        float* bsum = (float*)((char*)d_ws + 139264);             // 256 B
        prep_wfrag<<<272, 256, 0, stream>>>(W, Bv, wf, bsum);
        hdc_mfma<<<2048, 256, 0, stream>>>(x, wf, bsum, out);
    } else {
        float* weff = (float*)d_ws;
        float* bsum = weff + (size_t)CIN * NTAP * COUT;
        prep_weff_fb<<<(CIN * NTAP * COUT + 255) / 256, 256, 0, stream>>>(W, Bv, weff, bsum);
        hdc_fb<<<NB * HH, 256, 0, stream>>>(x, weff, bsum, out);
    }
}

// Round 18
// 88.260 us; speedup vs baseline: 1.4041x; 1.4041x over previous
//
#include <hip/hip_runtime.h>
#include <hip/hip_bf16.h>
#include <stdint.h>

typedef float  f32x4 __attribute__((ext_vector_type(4)));
typedef short  s16x8 __attribute__((ext_vector_type(8)));

#define NB    8
#define CIN   64
#define COUT  64
#define HH    128
#define WW    512
#define NTAP  17
#define PADW  152
#define XROW  816            // PADW + WW + PADW
#define BUFB  (XROW * 64)    // 52,224 B
#define HW    (HH * WW)

// ---------------------------------------------------------------------------
// weights in A-fragment order: byte off = (2t+p)*4096 + m*1024 + lane*16
__global__ __launch_bounds__(256) void prep_wfrag(
        const float* __restrict__ W, const float* __restrict__ Bv,
        __hip_bfloat16* __restrict__ wf, float* __restrict__ bsum) {
    int idx = blockIdx.x * 256 + threadIdx.x;      // 69,632 total
    if (idx < NTAP * 2 * 4 * 64 * 8) {
        int j  = idx & 7;
        int l  = (idx >> 3) & 63;
        int m  = (idx >> 9) & 3;
        int pp = (idx >> 11) & 1;
        int t  = idx >> 12;
        int ci = pp * 32 + 8 * (l >> 4) + j;
        int co = 16 * m + (l & 15);
        float v;
        if (t == 0) {
            v = 0.f;
            #pragma unroll
            for (int i = 0; i < NB; ++i) v += W[((i * COUT + co) * CIN + ci) * 3 + 1];
        } else if (t <= 8) {
            v = W[(((t - 1) * COUT + co) * CIN + ci) * 3 + 0];
        } else {
            v = W[(((t - 9) * COUT + co) * CIN + ci) * 3 + 2];
        }
        wf[idx] = __float2bfloat16(v);
    }
    if (idx < COUT) {
        float s = 0.f;
        #pragma unroll
        for (int i = 0; i < NB; ++i) s += Bv[i * COUT + idx];
        bsum[idx] = s;
    }
}

static constexpr int OFFS[NTAP] = {0, -48, -76, -96, -111, -124, -135, -144, -152,
                                      48,  76,  96,  111,  124,  135,  144,  152};

#define SB __builtin_amdgcn_sched_barrier(0)

#define LOADAF(AF, T0, CNT)                                                    \
    _Pragma("unroll")                                                          \
    for (int i = 0; i < (CNT); ++i)                                            \
        _Pragma("unroll")                                                      \
        for (int m = 0; m < 4; ++m)                                            \
            AF[i][m] = *reinterpret_cast<const s16x8*>(                        \
                wbase + ((T0) + i) * 8192 + m * 1024);

#define COMPTAPS(AF, T0, CNT)                                                  \
    _Pragma("unroll")                                                          \
    for (int i = 0; i < (CNT); ++i) {                                          \
        const int t      = (T0) + i;                                           \
        const int ldsrow = rowb + OFFS[t];                                     \
        const int slot   = lhi ^ ((ldsrow >> 1) & 3);                          \
        const char* bbase = smem + ldsrow * 64 + slot * 16;                    \
        s16x8 bfr[8];                                                          \
        _Pragma("unroll")                                                      \
        for (int n = 0; n < 8; ++n)                                            \
            bfr[n] = *reinterpret_cast<const s16x8*>(bbase + n * 1024);        \
        _Pragma("unroll")                                                      \
        for (int m = 0; m < 4; ++m)                                            \
            _Pragma("unroll")                                                  \
            for (int n = 0; n < 8; ++n)                                        \
                acc[m][n] = __builtin_amdgcn_mfma_f32_16x16x32_bf16(           \
                    AF[i][m], bfr[n], acc[m][n], 0, 0, 0);                     \
    }

// Fused main, the unexplored geometry cell: m=4 n=8 (B-LDS reads NOT
// duplicated across waves -> LDS pipe 22us, half of m2's 43.5) + single
// 52KB buffer + __launch_bounds__(256,2) -> TWO blocks/CU (the R5/R17
// lesson: cross-block TLP beats every intra-block schedule; every
// 1-block/CU persistent variant landed 72-112us). Block = one (b,h) row,
// 4 waves, 2 units (p-halves). SLOAD(p1) embedded AFTER the last af load
// of compute(p0) (R12 in-order-vmcnt lesson); compiler inserts exact
// reg-dep waits; plain __syncthreads(); other resident block covers drains.
__global__ __launch_bounds__(256, 2) void hdc_mfma(
        const float* __restrict__ x, const __hip_bfloat16* __restrict__ wf,
        const float* __restrict__ bsum, float* __restrict__ out) {
    __shared__ __align__(16) char smem[BUFB];

    const int tid  = threadIdx.x;
    const int wv   = tid >> 6;                     // wave 0..3
    const int lane = tid & 63;
    const int l15  = lane & 15;
    const int lhi  = lane >> 4;
    const int c    = wv;                           // staging chunk 0..3
    const int wl   = tid & 63;                     // staging w/4 index
    const int row  = blockIdx.x;                   // (b,h) row
    const int b    = row >> 7, h = row & 127;
    const int wlo  = wv * 128;                     // wave's 128-w slice (n=8)
    const int rowb = PADW + wlo + l15;

    f32x4 acc[4][8];
    #pragma unroll
    for (int m = 0; m < 4; ++m) {
        f32x4 bi = *reinterpret_cast<const f32x4*>(bsum + 16 * m + 4 * lhi);
        #pragma unroll
        for (int n = 0; n < 8; ++n) acc[m][n] = bi;
    }

    // zero halos once (SWRITE only touches body rows [PADW, PADW+512))
    {
        const int4 z{0, 0, 0, 0};
        int4* base = reinterpret_cast<int4*>(smem);
        for (int f = tid; f < 608; f += 256) {
            base[f] = z;                           // left halo  rows [0,152)
            base[2656 + f] = z;                    // right halo rows [664,816)
        }
    }

    float4 xv[8];                                  // staged fp32: 8 ci x 4 w

    // load half hf (256 w) of unit p into regs: 8 x dwordx4, coalesced
    auto SLOAD = [&](int p, int hf) {
        const float* src = x +
            (((size_t)(b * CIN + p * 32 + c * 8) * HH + h) * WW) +
            hf * 256 + wl * 4;
        #pragma unroll
        for (int j = 0; j < 8; ++j)
            xv[j] = *reinterpret_cast<const float4*>(src + j * HW);
    };
    // cvt + swizzled LDS write of half hf
    auto SWRITE = [&](int hf) {
        #pragma unroll
        for (int k = 0; k < 4; ++k) {
            const int r    = PADW + hf * 256 + wl * 4 + k;
            const int slot = c ^ ((r >> 1) & 3);
            union { __hip_bfloat16 hs[8]; int4 iv; } pk;
            #pragma unroll
            for (int j = 0; j < 8; ++j)
                pk.hs[j] = __float2bfloat16(((const float*)&xv[j])[k]);
            *reinterpret_cast<int4*>(smem + r * 64 + slot * 16) = pk.iv;
        }
    };

    // prologue: fill unit 0 (both halves)
    SLOAD(0, 0); SWRITE(0);
    SLOAD(0, 1); SWRITE(1);
    __syncthreads();

    #pragma unroll
    for (int p = 0; p < 2; ++p) {
        const char* wbase = (const char*)wf + p * 4096 + lane * 16;

        s16x8 afA[2][4], afB[2][4];                // 2-tap ping-pong batches

        LOADAF(afA, 0, 2)    SB;
        LOADAF(afB, 2, 2)    SB;
        COMPTAPS(afA, 0, 2)  SB;
        LOADAF(afA, 4, 2)    SB;
        COMPTAPS(afB, 2, 2)  SB;
        LOADAF(afB, 6, 2)    SB;
        COMPTAPS(afA, 4, 2)  SB;
        LOADAF(afA, 8, 2)    SB;
        COMPTAPS(afB, 6, 2)  SB;
        LOADAF(afB, 10, 2)   SB;
        COMPTAPS(afA, 8, 2)  SB;
        LOADAF(afA, 12, 2)   SB;
        COMPTAPS(afB, 10, 2) SB;
        LOADAF(afB, 14, 2)   SB;
        COMPTAPS(afA, 12, 2) SB;
        LOADAF(afA, 16, 1)   SB;                   // last af load...
        if (p == 0) SLOAD(1, 0);                   // ...then x-prefetch (newest)
        SB;
        COMPTAPS(afB, 14, 2) SB;                   // waits only afB (older)
        COMPTAPS(afA, 16, 1) SB;                   // waits only afA (older)

        __syncthreads();                           // all waves done reading

        if (p == 0) {
            SWRITE(0);                             // xv (unit1 half0) -> LDS
            SLOAD(1, 1);
            SWRITE(1);                             // compiler waits xv deps
            __syncthreads();                       // unit1 staged for all
        }
    }

    // epilogue: ReLU + store. D layout: col=l15 (w), row=4*lhi+rr (co)
    float* obase = out + (((size_t)b * COUT + 4 * lhi) * HH + h) * WW + wlo + l15;
    #pragma unroll
    for (int m = 0; m < 4; ++m)
        #pragma unroll
        for (int n = 0; n < 8; ++n)
            #pragma unroll
            for (int rr = 0; rr < 4; ++rr) {
                float v = acc[m][n][rr];
                obase[(size_t)(16 * m + rr) * HW + 16 * n] = v > 0.f ? v : 0.f;
            }
}

// ---------------------------------------------------------------------------
// FALLBACK (round-1 fp32 kernel) if ws_size is too small for weight scratch
// ---------------------------------------------------------------------------
#define CI_STAGE 16

__global__ void prep_weff_fb(const float* __restrict__ W, const float* __restrict__ Bv,
                             float* __restrict__ weff, float* __restrict__ bsum) {
    int idx = blockIdx.x * 256 + threadIdx.x;
    if (idx < CIN * NTAP * COUT) {
        int co = idx & 63;
        int t  = (idx >> 6) % NTAP;
        int ci = idx / (NTAP * COUT);
        float v;
        if (t == 0) {
            v = 0.f;
            #pragma unroll
            for (int i = 0; i < NB; ++i) v += W[(((i * COUT + co) * CIN + ci) * 3) + 1];
        } else if (t <= 8) {
            v = W[((((t - 1) * COUT + co) * CIN + ci) * 3) + 0];
        } else {
            v = W[((((t - 9) * COUT + co) * CIN + ci) * 3) + 2];
        }
        weff[(ci * NTAP + t) * COUT + co] = v;
    }
    if (idx < COUT) {
        float s = 0.f;
        #pragma unroll
        for (int i = 0; i < NB; ++i) s += Bv[i * COUT + idx];
        bsum[idx] = s;
    }
}

__global__ __launch_bounds__(256, 2) void hdc_fb(
        const float* __restrict__ x, const float* __restrict__ weff,
        const float* __restrict__ bsum, float* __restrict__ out) {
    __shared__ float xsf[CI_STAGE][XROW];
    const int bh  = blockIdx.x;
    const int b   = bh >> 7;
    const int h   = bh & (HH - 1);
    const int tid = threadIdx.x;
    const int cg  = tid >> 5;
    const int wl  = tid & 31;
    float acc[8][16];
    #pragma unroll
    for (int j = 0; j < 8; ++j) {
        const float bj = bsum[cg * 8 + j];
        #pragma unroll
        for (int i = 0; i < 16; ++i) acc[j][i] = bj;
    }
    const float* xrowbase = x + ((size_t)(b * CIN) * HH + h) * WW;
    for (int s = 0; s < CIN / CI_STAGE; ++s) {
        __syncthreads();
        for (int f = tid; f < CI_STAGE * PADW; f += 256) {
            int r = f / PADW, cc = f - r * PADW;
            xsf[r][cc] = 0.f;
            xsf[r][PADW + WW + cc] = 0.f;
        }
        #pragma unroll
        for (int j = 0; j < 8; ++j) {
            int flat = j * 256 + tid;
            int r = flat >> 7, c4 = flat & 127;
            const float4 v = *reinterpret_cast<const float4*>(
                xrowbase + (size_t)(s * CI_STAGE + r) * HW + c4 * 4);
            *reinterpret_cast<float4*>(&xsf[r][PADW + c4 * 4]) = v;
        }
        __syncthreads();
        for (int r = 0; r < CI_STAGE; ++r) {
            const int ci = s * CI_STAGE + r;
            const float* wrow = weff + (size_t)(ci * NTAP) * COUT + cg * 8;
            const float* xr   = &xsf[r][PADW + wl];
            #pragma unroll
            for (int t = 0; t < NTAP; ++t) {
                const float4 w0 = *reinterpret_cast<const float4*>(wrow + t * COUT);
                const float4 w1 = *reinterpret_cast<const float4*>(wrow + t * COUT + 4);
                float xvv[16];
                #pragma unroll
                for (int i = 0; i < 16; ++i) xvv[i] = xr[OFFS[t] + 32 * i];
                const float wv2[8] = {w0.x, w0.y, w0.z, w0.w, w1.x, w1.y, w1.z, w1.w};
                #pragma unroll
                for (int j = 0; j < 8; ++j)
                    #pragma unroll
                    for (int i = 0; i < 16; ++i)
                        acc[j][i] = fmaf(wv2[j], xvv[i], acc[j][i]);
            }
        }
    }
    float* outbase = out + (((size_t)b * COUT + cg * 8) * HH + h) * WW + wl;
    #pragma unroll
    for (int j = 0; j < 8; ++j)
        #pragma unroll
        for (int i = 0; i < 16; ++i) {
            float v = acc[j][i];
            outbase[(size_t)j * HW + 32 * i] = v > 0.f ? v : 0.f;
        }
}

// ---------------------------------------------------------------------------

extern "C" void kernel_launch(void* const* d_in, const int* in_sizes, int n_in,
                              void* d_out, int out_size, void* d_ws, size_t ws_size,
                              hipStream_t stream) {
    const float* x  = (const float*)d_in[0];
    const float* W  = (const float*)d_in[1];
    const float* Bv = (const float*)d_in[2];
    float* out = (float*)d_out;

    const size_t need = 139264 + 256;              // wf + bsum

    if (ws_size >= need) {
        __hip_bfloat16* wf = (__hip_bfloat16*)d_ws;               // 139,264 B
        float* bsum = (float*)((char*)d_ws + 139264);             // 256 B
        prep_wfrag<<<272, 256, 0, stream>>>(W, Bv, wf, bsum);
        hdc_mfma<<<1024, 256, 0, stream>>>(x, wf, bsum, out);
    } else {
        float* weff = (float*)d_ws;
        float* bsum = weff + (size_t)CIN * NTAP * COUT;
        prep_weff_fb<<<(CIN * NTAP * COUT + 255) / 256, 256, 0, stream>>>(W, Bv, weff, bsum);
        hdc_fb<<<NB * HH, 256, 0, stream>>>(x, weff, bsum, out);
    }
}

// Round 19
// 88.199 us; speedup vs baseline: 1.4051x; 1.0007x over previous
//
#include <hip/hip_runtime.h>
#include <hip/hip_bf16.h>
#include <stdint.h>

typedef float  f32x4  __attribute__((ext_vector_type(4)));
typedef float  f32x16 __attribute__((ext_vector_type(16)));
typedef short  s16x8  __attribute__((ext_vector_type(8)));

#define NB    8
#define CIN   64
#define COUT  64
#define HH    128
#define WW    512
#define NTAP  17
#define PADW  152
#define XROW  816            // PADW + WW + PADW
#define BUFB  (XROW * 64)    // 52,224 B
#define HW    (HH * WW)

// ---------------------------------------------------------------------------
// weights in 32x32 A-fragment order:
//   byte off = ((t*2+p)*4 + mt*2 + kc)*1024 + lane*16
//   content: weff[t][ci = p*32 + kc*16 + 8*(lane>>5) + j][co = mt*32 + (lane&31)]
__global__ __launch_bounds__(256) void prep_wfrag(
        const float* __restrict__ W, const float* __restrict__ Bv,
        __hip_bfloat16* __restrict__ wf, float* __restrict__ bsum) {
    int idx = blockIdx.x * 256 + threadIdx.x;      // 69,632 total
    if (idx < NTAP * 2 * 2 * 2 * 64 * 8) {
        int j  = idx & 7;
        int l  = (idx >> 3) & 63;
        int kc = (idx >> 9) & 1;
        int mt = (idx >> 10) & 1;
        int pp = (idx >> 11) & 1;
        int t  = idx >> 12;
        int ci = pp * 32 + kc * 16 + 8 * (l >> 5) + j;
        int co = mt * 32 + (l & 31);
        float v;
        if (t == 0) {
            v = 0.f;
            #pragma unroll
            for (int i = 0; i < NB; ++i) v += W[((i * COUT + co) * CIN + ci) * 3 + 1];
        } else if (t <= 8) {
            v = W[(((t - 1) * COUT + co) * CIN + ci) * 3 + 0];
        } else {
            v = W[(((t - 9) * COUT + co) * CIN + ci) * 3 + 2];
        }
        wf[idx] = __float2bfloat16(v);
    }
    if (idx < COUT) {
        float s = 0.f;
        #pragma unroll
        for (int i = 0; i < NB; ++i) s += Bv[i * COUT + idx];
        bsum[idx] = s;
    }
}

static constexpr int OFFS[NTAP] = {0, -48, -76, -96, -111, -124, -135, -144, -152,
                                      48,  76,  96,  111,  124,  135,  144,  152};

#define SB __builtin_amdgcn_sched_barrier(0)

// af[mt][kc] for tap T
#define LOADAF(AF, T)                                                          \
    _Pragma("unroll")                                                          \
    for (int mt = 0; mt < 2; ++mt)                                             \
        _Pragma("unroll")                                                      \
        for (int kc = 0; kc < 2; ++kc)                                         \
            AF[mt][kc] = *reinterpret_cast<const s16x8*>(                      \
                wbase + (T) * 8192 + (mt * 2 + kc) * 1024);

// one tap: 8 ds_read_b128 + 16 x mfma_32x32x16 (B shared across mt)
#define COMPTAP(AF, T)                                                         \
    _Pragma("unroll")                                                          \
    for (int nt = 0; nt < 4; ++nt) {                                           \
        const int r_   = rowb + nt * 32 + OFFS[T];                             \
        const int s0   = l5 ^ ((r_ >> 1) & 3);                                 \
        const char* ba = smem + r_ * 64;                                       \
        s16x8 bf0 = *reinterpret_cast<const s16x8*>(ba + s0 * 16);             \
        s16x8 bf1 = *reinterpret_cast<const s16x8*>(ba + (s0 ^ 2) * 16);       \
        acc[0][nt] = __builtin_amdgcn_mfma_f32_32x32x16_bf16(                  \
            AF[0][0], bf0, acc[0][nt], 0, 0, 0);                               \
        acc[0][nt] = __builtin_amdgcn_mfma_f32_32x32x16_bf16(                  \
            AF[0][1], bf1, acc[0][nt], 0, 0, 0);                               \
        acc[1][nt] = __builtin_amdgcn_mfma_f32_32x32x16_bf16(                  \
            AF[1][0], bf0, acc[1][nt], 0, 0, 0);                               \
        acc[1][nt] = __builtin_amdgcn_mfma_f32_32x32x16_bf16(                  \
            AF[1][1], bf1, acc[1][nt], 0, 0, 0);                               \
    }

// Fused main with 32x32x16 MFMA: 1024 blocks x 256 thr (4 waves), wave =
// ALL 64 co (mt=2) x 128 w (nt=4). The 32x32 B-frag (1024B = 32w x 16ci)
// feeds 2 co-tiles -> per-row B-LDS traffic 1.09MB (half of 16x16 m2) with
// acc only 128 regs. Arch budget ~225 < 256 -> (256,2) gives 2 blocks/CU:
// the R5/m114 cross-block TLP that every 1-block variant lacked, without
// R18's spills. A/B frag ci<->lane-group maps are constructed identically
// (prep_wfrag + LDS read) so any permutation cancels; C/D layout is the
// m74/m101-verified col=lane&31, row=(r&3)+8*(r>>2)+4*(lane>>5).
__global__ __launch_bounds__(256, 2) void hdc_mfma(
        const float* __restrict__ x, const __hip_bfloat16* __restrict__ wf,
        const float* __restrict__ bsum, float* __restrict__ out) {
    __shared__ __align__(16) char smem[BUFB];

    const int tid  = threadIdx.x;
    const int wv   = tid >> 6;                     // wave 0..3
    const int lane = tid & 63;
    const int l31  = lane & 31;
    const int l5   = lane >> 5;                    // K-group 0/1
    const int c    = wv;                           // staging chunk 0..3
    const int wl   = tid & 63;                     // staging w/4 index
    const int row  = blockIdx.x;                   // (b,h) row
    const int b    = row >> 7, h = row & 127;
    const int wlo  = wv * 128;                     // wave's 128-w slice
    const int rowb = PADW + wlo + l31;

    f32x16 acc[2][4];
    #pragma unroll
    for (int mt = 0; mt < 2; ++mt)
        #pragma unroll
        for (int rq = 0; rq < 4; ++rq) {
            const f32x4 bi = *reinterpret_cast<const f32x4*>(
                bsum + mt * 32 + 8 * rq + 4 * l5);
            #pragma unroll
            for (int nt = 0; nt < 4; ++nt)
                #pragma unroll
                for (int e = 0; e < 4; ++e)
                    acc[mt][nt][4 * rq + e] = bi[e];
        }

    // zero halos once (SWRITE only touches body rows [PADW, PADW+512))
    {
        const int4 z{0, 0, 0, 0};
        int4* base = reinterpret_cast<int4*>(smem);
        for (int f = tid; f < 608; f += 256) {
            base[f] = z;                           // left halo  rows [0,152)
            base[2656 + f] = z;                    // right halo rows [664,816)
        }
    }

    float4 xv[8];                                  // staged fp32: 8 ci x 4 w

    auto SLOAD = [&](int p, int hf) {
        const float* src = x +
            (((size_t)(b * CIN + p * 32 + c * 8) * HH + h) * WW) +
            hf * 256 + wl * 4;
        #pragma unroll
        for (int j = 0; j < 8; ++j)
            xv[j] = *reinterpret_cast<const float4*>(src + j * HW);
    };
    auto SWRITE = [&](int hf) {
        #pragma unroll
        for (int k = 0; k < 4; ++k) {
            const int r    = PADW + hf * 256 + wl * 4 + k;
            const int slot = c ^ ((r >> 1) & 3);
            union { __hip_bfloat16 hs[8]; int4 iv; } pk;
            #pragma unroll
            for (int j = 0; j < 8; ++j)
                pk.hs[j] = __float2bfloat16(((const float*)&xv[j])[k]);
            *reinterpret_cast<int4*>(smem + r * 64 + slot * 16) = pk.iv;
        }
    };

    // prologue: fill unit 0 (both halves)
    SLOAD(0, 0); SWRITE(0);
    SLOAD(0, 1); SWRITE(1);
    __syncthreads();

    #pragma unroll
    for (int p = 0; p < 2; ++p) {
        const char* wbase = (const char*)wf + p * 4096 + lane * 16;

        s16x8 afA[2][2], afB[2][2];                // ping-pong af (1 tap each)

        LOADAF(afA, 0) SB;
        #pragma unroll
        for (int t = 0; t < 16; ++t) {
            if (t & 1) { LOADAF(afA, t + 1) SB; COMPTAP(afB, t) SB; }
            else       { LOADAF(afB, t + 1) SB; COMPTAP(afA, t) SB; }
        }
        if (p == 0) SLOAD(1, 0);                   // after ALL af loads (newest)
        SB;
        COMPTAP(afA, 16) SB;                       // waits only afA (older)

        __syncthreads();                           // all waves done reading

        if (p == 0) {
            SWRITE(0);                             // xv (unit1 half0) -> LDS
            SLOAD(1, 1);
            SWRITE(1);
            __syncthreads();                       // unit1 staged for all
        }
    }

    // epilogue: ReLU + store. 32x32 D: col=l31 (w), co=mt*32+4*l5+(r&3)+8*(r>>2)
    float* obase = out + (((size_t)b * COUT + 4 * l5) * HH + h) * WW + wlo + l31;
    #pragma unroll
    for (int mt = 0; mt < 2; ++mt)
        #pragma unroll
        for (int nt = 0; nt < 4; ++nt)
            #pragma unroll
            for (int r = 0; r < 16; ++r) {
                const int co_off = mt * 32 + (r & 3) + 8 * (r >> 2);
                float v = acc[mt][nt][r];
                obase[(size_t)co_off * HW + nt * 32] = v > 0.f ? v : 0.f;
            }
}

// ---------------------------------------------------------------------------
// FALLBACK (round-1 fp32 kernel) if ws_size is too small for weight scratch
// ---------------------------------------------------------------------------
#define CI_STAGE 16

__global__ void prep_weff_fb(const float* __restrict__ W, const float* __restrict__ Bv,
                             float* __restrict__ weff, float* __restrict__ bsum) {
    int idx = blockIdx.x * 256 + threadIdx.x;
    if (idx < CIN * NTAP * COUT) {
        int co = idx & 63;
        int t  = (idx >> 6) % NTAP;
        int ci = idx / (NTAP * COUT);
        float v;
        if (t == 0) {
            v = 0.f;
            #pragma unroll
            for (int i = 0; i < NB; ++i) v += W[(((i * COUT + co) * CIN + ci) * 3) + 1];
        } else if (t <= 8) {
            v = W[((((t - 1) * COUT + co) * CIN + ci) * 3) + 0];
        } else {
            v = W[((((t - 9) * COUT + co) * CIN + ci) * 3) + 2];
        }
        weff[(ci * NTAP + t) * COUT + co] = v;
    }
    if (idx < COUT) {
        float s = 0.f;
        #pragma unroll
        for (int i = 0; i < NB; ++i) s += Bv[i * COUT + idx];
        bsum[idx] = s;
    }
}

__global__ __launch_bounds__(256, 2) void hdc_fb(
        const float* __restrict__ x, const float* __restrict__ weff,
        const float* __restrict__ bsum, float* __restrict__ out) {
    __shared__ float xsf[CI_STAGE][XROW];
    const int bh  = blockIdx.x;
    const int b   = bh >> 7;
    const int h   = bh & (HH - 1);
    const int tid = threadIdx.x;
    const int cg  = tid >> 5;
    const int wl  = tid & 31;
    float acc[8][16];
    #pragma unroll
    for (int j = 0; j < 8; ++j) {
        const float bj = bsum[cg * 8 + j];
        #pragma unroll
        for (int i = 0; i < 16; ++i) acc[j][i] = bj;
    }
    const float* xrowbase = x + ((size_t)(b * CIN) * HH + h) * WW;
    for (int s = 0; s < CIN / CI_STAGE; ++s) {
        __syncthreads();
        for (int f = tid; f < CI_STAGE * PADW; f += 256) {
            int r = f / PADW, cc = f - r * PADW;
            xsf[r][cc] = 0.f;
            xsf[r][PADW + WW + cc] = 0.f;
        }
        #pragma unroll
        for (int j = 0; j < 8; ++j) {
            int flat = j * 256 + tid;
            int r = flat >> 7, c4 = flat & 127;
            const float4 v = *reinterpret_cast<const float4*>(
                xrowbase + (size_t)(s * CI_STAGE + r) * HW + c4 * 4);
            *reinterpret_cast<float4*>(&xsf[r][PADW + c4 * 4]) = v;
        }
        __syncthreads();
        for (int r = 0; r < CI_STAGE; ++r) {
            const int ci = s * CI_STAGE + r;
            const float* wrow = weff + (size_t)(ci * NTAP) * COUT + cg * 8;
            const float* xr   = &xsf[r][PADW + wl];
            #pragma unroll
            for (int t = 0; t < NTAP; ++t) {
                const float4 w0 = *reinterpret_cast<const float4*>(wrow + t * COUT);
                const float4 w1 = *reinterpret_cast<const float4*>(wrow + t * COUT + 4);
                float xvv[16];
                #pragma unroll
                for (int i = 0; i < 16; ++i) xvv[i] = xr[OFFS[t] + 32 * i];
                const float wv2[8] = {w0.x, w0.y, w0.z, w0.w, w1.x, w1.y, w1.z, w1.w};
                #pragma unroll
                for (int j = 0; j < 8; ++j)
                    #pragma unroll
                    for (int i = 0; i < 16; ++i)
                        acc[j][i] = fmaf(wv2[j], xvv[i], acc[j][i]);
            }
        }
    }
    float* outbase = out + (((size_t)b * COUT + cg * 8) * HH + h) * WW + wl;
    #pragma unroll
    for (int j = 0; j < 8; ++j)
        #pragma unroll
        for (int i = 0; i < 16; ++i) {
            float v = acc[j][i];
            outbase[(size_t)j * HW + 32 * i] = v > 0.f ? v : 0.f;
        }
}

// ---------------------------------------------------------------------------

extern "C" void kernel_launch(void* const* d_in, const int* in_sizes, int n_in,
                              void* d_out, int out_size, void* d_ws, size_t ws_size,
                              hipStream_t stream) {
    const float* x  = (const float*)d_in[0];
    const float* W  = (const float*)d_in[1];
    const float* Bv = (const float*)d_in[2];
    float* out = (float*)d_out;

    const size_t need = 139264 + 256;              // wf + bsum

    if (ws_size >= need) {
        __hip_bfloat16* wf = (__hip_bfloat16*)d_ws;               // 139,264 B
        float* bsum = (float*)((char*)d_ws + 139264);             // 256 B
        prep_wfrag<<<272, 256, 0, stream>>>(W, Bv, wf, bsum);
        hdc_mfma<<<1024, 256, 0, stream>>>(x, wf, bsum, out);
    } else {
        float* weff = (float*)d_ws;
        float* bsum = weff + (size_t)CIN * NTAP * COUT;
        prep_weff_fb<<<(CIN * NTAP * COUT + 255) / 256, 256, 0, stream>>>(W, Bv, weff, bsum);
        hdc_fb<<<NB * HH, 256, 0, stream>>>(x, weff, bsum, out);
    }
}